// Round 3
// baseline (347.158 us; speedup 1.0000x reference)
//
#include <hip/hip_runtime.h>

// iRPE contextual/transposed PRODUCT:
//   lt[b,h,i,k] = sum_d x[b,h,i,d] * W[h,d,k]   (K=49 GEMV per row)
//   out[b,h,i,j] = lt[b,h,i, bucket[i,j]]        (the 256 MB write)
//
// Round-3 theory: previous kernels wrote 4-KB pieces at 4-MB stride ->
// HBM row-buffer thrash (~1.9 TB/s vs 6.15 TB/s fill ceiling). This version
// makes each block write 16 contiguous 16-KB spans (4 consecutive i rows x
// 16 bh planes), each wave streaming 4 spans linearly like the fill kernel.
// Bucket rows are register-cached (16 int4/thread); the 4 consecutive-gid
// blocks sharing an igrp reuse them via L2, so bucket HBM traffic stays ~6 MB.

constexpr int cL = 1024;
constexpr int cD = 64;
constexpr int cK = 49;
constexpr int IG = 4;    // consecutive i rows per block
constexpr int BG = 16;   // bh planes per block

__global__ __launch_bounds__(256, 4) void irpe_fused(
    const float* __restrict__ x,       // (B,H,L,D) = (bh, i, d)
    const float* __restrict__ W,       // (H,D,K)
    const int*   __restrict__ bucket,  // (L,L), values in [0,49)
    float*       __restrict__ out)     // (B,H,L,L)
{
    __shared__ float xs[BG * IG][cD];      // 16 KB: x rows for this block
    __shared__ float lts[BG * IG * cK];    // 12.25 KB: lt values

    const int gid  = blockIdx.x;
    const int igrp = gid >> 2;             // consecutive gids share igrp (L2 bucket reuse)
    const int bhg  = gid & 3;
    const int i0   = igrp * IG;
    const int bh0  = bhg * BG;
    const int tid  = threadIdx.x;
    const int lane = tid & 63;
    const int w    = tid >> 6;

    // ---- Phase A: stage x rows (64 rows x 256 B, coalesced float4) ----
    const float4* x4 = (const float4*)x;
    #pragma unroll
    for (int rr = 0; rr < 4; ++rr) {
        const int idx = rr * 256 + tid;
        const int row = idx >> 4;          // 0..63 (= lhb*IG + li)
        const int d4  = idx & 15;
        const int lhb = row >> 2;
        const int li  = row & 3;
        float4 v = x4[((size_t)(bh0 + lhb) * cL + (i0 + li)) * (cD / 4) + d4];
        ((float4*)xs[row])[d4] = v;
    }

    // ---- bucket rows -> registers (each wave loads same 16 int4; L2-hit) ----
    int4 bkt[IG * 4];
    #pragma unroll
    for (int t = 0; t < IG * 4; ++t) {
        const int li = t >> 2;
        const int jc = t & 3;
        bkt[t] = ((const int4*)(bucket + (size_t)(i0 + li) * cL + jc * 256))[lane];
    }

    __syncthreads();

    // ---- Phase B: lts[row*49+k] = sum_d xs[row][d] * W[h,d,k] ----
    // Consecutive lanes -> consecutive k => coalesced W loads (L2-resident).
    for (int p = tid; p < BG * IG * cK; p += 256) {
        const int row = p / cK;
        const int k   = p - row * cK;
        const int lhb = row >> 2;
        const int h   = lhb & 7;           // (bh0 + lhb) & 7 == lhb & 7 (bh0 % 8 == 0)
        const float* wp = W + (size_t)h * cD * cK + k;
        const float* xr = xs[row];
        float acc = 0.0f;
        #pragma unroll
        for (int d = 0; d < cD; ++d)
            acc = fmaf(xr[d], wp[d * cK], acc);
        lts[p] = acc;
    }
    __syncthreads();

    // ---- Phase C: wave w streams planes lhb = w*4 .. w*4+3 ----
    // Each plane chunk = 4 consecutive i rows = 16 KB CONTIGUOUS, walked in
    // ascending address order (t = li*4 + jc).
    #pragma unroll
    for (int q = 0; q < 4; ++q) {
        const int lhb = w * 4 + q;
        float4* pb = (float4*)(out + ((size_t)(bh0 + lhb) * cL + i0) * cL);
        const float* lbase = lts + lhb * (IG * cK);
        #pragma unroll 4
        for (int t = 0; t < IG * 4; ++t) {
            const int li = t >> 2;
            const float* lrow = lbase + li * cK;
            const int4 bk = bkt[t];
            float4 o;
            o.x = lrow[bk.x];
            o.y = lrow[bk.y];
            o.z = lrow[bk.z];
            o.w = lrow[bk.w];
            pb[t * 64 + lane] = o;         // contiguous 16-KB walk per (q)
        }
    }
}

extern "C" void kernel_launch(void* const* d_in, const int* in_sizes, int n_in,
                              void* d_out, int out_size, void* d_ws, size_t ws_size,
                              hipStream_t stream) {
    const float* x      = (const float*)d_in[0];   // (8,8,1024,64) fp32
    const float* W      = (const float*)d_in[1];   // (8,64,49) fp32
    const int*   bucket = (const int*)d_in[2];     // (1024,1024) int32
    float*       out    = (float*)d_out;           // (8,8,1024,1024) fp32

    const int grid = (cL / IG) * (64 / BG);        // 256 * 4 = 1024 blocks
    irpe_fused<<<grid, 256, 0, stream>>>(x, W, bucket, out);
}

// Round 4
// 310.968 us; speedup vs baseline: 1.1164x; 1.1164x over previous
//
#include <hip/hip_runtime.h>

// iRPE contextual/transposed PRODUCT:
//   lt[b,h,i,k] = sum_d x[b,h,i,d] * W[h,d,k]   (K=49 GEMV per row)
//   out[b,h,i,j] = lt[b,h,i, bucket[i,j]]        (the 256 MB write)
//
// Round-4: identical structure to round-2 (fastest so far: 2048 blocks,
// 14.2 KB LDS, 8 blocks/CU) with ONE change: phase-C output stores are
// NON-TEMPORAL (bypass L2/L3 allocate). Theory: the harness's 1-GiB poison
// fill leaves L3 full of dirty lines; write-allocating stores pay a dirty
// eviction per line (~2x effective write traffic). nt stores stream to HBM.

constexpr int cL = 1024;
constexpr int cD = 64;
constexpr int cK = 49;
constexpr int cHALF = 32; // bh rows per block

typedef float vf4 __attribute__((ext_vector_type(4)));

__global__ __launch_bounds__(256) void irpe_fused(
    const float* __restrict__ x,       // (B,H,L,D) = (bh, i, d)
    const float* __restrict__ W,       // (H,D,K)
    const int*   __restrict__ bucket,  // (L,L), values in [0,49)
    float*       __restrict__ out)     // (B,H,L,L)
{
    __shared__ vf4  xs4[cHALF][cD / 4];   // x[lh][d] as float4, 8 KB
    __shared__ float lts[cHALF * cK];     // lt values, 6.1 KB

    const int gid  = blockIdx.x;
    const int i    = gid >> 1;            // row of bucket / x
    const int bh0  = (gid & 1) * cHALF;   // which half of the 64 bh rows
    const int tid  = threadIdx.x;

    // ---- Phase A: stage x rows (32 x 256 B, coalesced float4, nt loads) ----
    const vf4* x4 = (const vf4*)x;
    #pragma unroll
    for (int r = 0; r < 2; ++r) {
        const int idx = r * 256 + tid;
        const int lh  = idx >> 4;         // 0..31
        const int d4  = idx & 15;         // 0..15
        xs4[lh][d4] = __builtin_nontemporal_load(
            &x4[((size_t)(bh0 + lh) * cL + i) * (cD / 4) + d4]);
    }

    // bucket row i -> registers, reused for all 32 output rows (L2-cached,
    // shared by the paired block and the 64 bh planes)
    const int4 bk = ((const int4*)(bucket + (size_t)i * cL))[tid];

    __syncthreads();

    // ---- Phase B: lts[lh*49+k] = sum_d xs[lh][d] * W[h,d,k] ----
    // Consecutive lanes -> consecutive k => coalesced W loads (L2-resident).
    const float* xsf = (const float*)xs4;
    for (int p = tid; p < cHALF * cK; p += 256) {
        const int lh = p / cK;
        const int k  = p - lh * cK;
        const int h  = (bh0 + lh) & 7;
        const float* wp = W + (size_t)h * cD * cK + k;
        const float* xr = xsf + lh * cD;
        float acc = 0.0f;
        #pragma unroll
        for (int d = 0; d < cD; ++d) {
            acc = fmaf(xr[d], wp[(size_t)d * cK], acc);
        }
        lts[p] = acc;
    }
    __syncthreads();

    // ---- Phase C: gather + stream 32 x 4 KB stores, NON-TEMPORAL ----
    vf4* obase = (vf4*)(out + ((size_t)bh0 * cL + i) * cL);
    #pragma unroll 4
    for (int lh = 0; lh < cHALF; ++lh) {
        const float* lrow = lts + lh * cK;
        vf4 o;
        o.x = lrow[bk.x];
        o.y = lrow[bk.y];
        o.z = lrow[bk.z];
        o.w = lrow[bk.w];
        __builtin_nontemporal_store(o, &obase[(size_t)lh * cL * (cL / 4) + tid]);
    }
}

extern "C" void kernel_launch(void* const* d_in, const int* in_sizes, int n_in,
                              void* d_out, int out_size, void* d_ws, size_t ws_size,
                              hipStream_t stream) {
    const float* x      = (const float*)d_in[0];   // (8,8,1024,64) fp32
    const float* W      = (const float*)d_in[1];   // (8,64,49) fp32
    const int*   bucket = (const int*)d_in[2];     // (1024,1024) int32
    float*       out    = (float*)d_out;           // (8,8,1024,1024) fp32

    const int grid = cL * 2;                        // 2048 blocks
    irpe_fused<<<grid, 256, 0, stream>>>(x, W, bucket, out);
}

// Round 5
// 302.767 us; speedup vs baseline: 1.1466x; 1.0271x over previous
//
#include <hip/hip_runtime.h>

// iRPE contextual/transposed PRODUCT:
//   lt[b,h,i,k] = sum_d x[b,h,i,d] * W[h,d,k]   (K=49 GEMV per row)
//   out[b,h,i,j] = lt[b,h,i, bucket[i,j]]        (the 256 MB write)
//
// Round-5: r4 kernel (NT stores, 2048 blocks, 8/CU) with ONE change: the
// gid -> (i, half) mapping is swizzled so co-resident blocks on a CU cover
// all 8 residues of i mod 8. Output channel bits [12:14] come from i mod 8
// (bh contributes none: 4-MB stride); with the old linear mapping every
// block on a CU shared the same i mod 8 -> its whole 1 MB of stores hit
// 1/8 of the HBM channel groups. New mapping: gid = i_lo*256 + i_hi*2 + half.

constexpr int cL = 1024;
constexpr int cD = 64;
constexpr int cK = 49;
constexpr int cHALF = 32; // bh rows per block

typedef float vf4 __attribute__((ext_vector_type(4)));

__global__ __launch_bounds__(256) void irpe_fused(
    const float* __restrict__ x,       // (B,H,L,D) = (bh, i, d)
    const float* __restrict__ W,       // (H,D,K)
    const int*   __restrict__ bucket,  // (L,L), values in [0,49)
    float*       __restrict__ out)     // (B,H,L,L)
{
    __shared__ vf4  xs4[cHALF][cD / 4];   // x[lh][d] as float4, 8 KB
    __shared__ float lts[cHALF * cK];     // lt values, 6.1 KB

    // ---- swizzled block -> (i, half) mapping ----
    // gid = i_lo*256 + i_hi*2 + half;  i = i_hi*8 + i_lo
    // Round-robin CU assignment (stride 256) walks i_lo through all 8
    // residues -> a CU's resident blocks cover all channel-bit groups.
    const int gid  = blockIdx.x;
    const int i_lo = gid >> 8;            // 0..7
    const int rest = gid & 255;
    const int i_hi = rest >> 1;           // 0..127
    const int half = gid & 1;
    const int i    = i_hi * 8 + i_lo;     // 0..1023
    const int bh0  = half * cHALF;
    const int tid  = threadIdx.x;

    // ---- Phase A: stage x rows (32 x 256 B, coalesced float4, nt loads) ----
    const vf4* x4 = (const vf4*)x;
    #pragma unroll
    for (int r = 0; r < 2; ++r) {
        const int idx = r * 256 + tid;
        const int lh  = idx >> 4;         // 0..31
        const int d4  = idx & 15;         // 0..15
        xs4[lh][d4] = __builtin_nontemporal_load(
            &x4[((size_t)(bh0 + lh) * cL + i) * (cD / 4) + d4]);
    }

    // bucket row i -> registers, reused for all 32 output rows (L2-cached;
    // the paired half-block with the same i shares it)
    const int4 bk = ((const int4*)(bucket + (size_t)i * cL))[tid];

    __syncthreads();

    // ---- Phase B: lts[lh*49+k] = sum_d xs[lh][d] * W[h,d,k] ----
    // Consecutive lanes -> consecutive k => coalesced W loads (L2-resident).
    const float* xsf = (const float*)xs4;
    for (int p = tid; p < cHALF * cK; p += 256) {
        const int lh = p / cK;
        const int k  = p - lh * cK;
        const int h  = (bh0 + lh) & 7;
        const float* wp = W + (size_t)h * cD * cK + k;
        const float* xr = xsf + lh * cD;
        float acc = 0.0f;
        #pragma unroll
        for (int d = 0; d < cD; ++d) {
            acc = fmaf(xr[d], wp[(size_t)d * cK], acc);
        }
        lts[p] = acc;
    }
    __syncthreads();

    // ---- Phase C: gather + stream 32 x 4 KB stores, NON-TEMPORAL ----
    vf4* obase = (vf4*)(out + ((size_t)bh0 * cL + i) * cL);
    #pragma unroll 4
    for (int lh = 0; lh < cHALF; ++lh) {
        const float* lrow = lts + lh * cK;
        vf4 o;
        o.x = lrow[bk.x];
        o.y = lrow[bk.y];
        o.z = lrow[bk.z];
        o.w = lrow[bk.w];
        __builtin_nontemporal_store(o, &obase[(size_t)lh * cL * (cL / 4) + tid]);
    }
}

extern "C" void kernel_launch(void* const* d_in, const int* in_sizes, int n_in,
                              void* d_out, int out_size, void* d_ws, size_t ws_size,
                              hipStream_t stream) {
    const float* x      = (const float*)d_in[0];   // (8,8,1024,64) fp32
    const float* W      = (const float*)d_in[1];   // (8,64,49) fp32
    const int*   bucket = (const int*)d_in[2];     // (1024,1024) int32
    float*       out    = (float*)d_out;           // (8,8,1024,1024) fp32

    const int grid = cL * 2;                        // 2048 blocks
    irpe_fused<<<grid, 256, 0, stream>>>(x, W, bucket, out);
}